// Round 1
// baseline (828.563 us; speedup 1.0000x reference)
//
#include <hip/hip_runtime.h>
#include <cstdint>
#include <cstddef>

constexpr int N_NODES = 100000;
constexpr int N_EDGES = 1600000;
constexpr int F_IN   = 128;
constexpr int F_HID  = 128;
constexpr int F_OUT  = 40;
constexpr float BN_EPS = 1e-5f;

// ---------------- helpers ----------------
__device__ inline float lane_bcast(float v, int l) {
    return __uint_as_float(__builtin_amdgcn_readlane(__float_as_uint(v), l));
}

// ---------------- CSR build ----------------
__global__ void k_count(const int* __restrict__ dst, int* __restrict__ cnt) {
    int e = blockIdx.x * 256 + threadIdx.x;
    if (e < N_EDGES) atomicAdd(&cnt[dst[e]], 1);
}

__global__ void k_dinv(const int* __restrict__ cnt, float* __restrict__ dinv) {
    int v = blockIdx.x * 256 + threadIdx.x;
    if (v < N_NODES) dinv[v] = rsqrtf((float)(cnt[v] + 1));  // +1 self-loop
}

__global__ void k_scan1(const int* __restrict__ cnt, int* __restrict__ rowptr,
                        int* __restrict__ bsum) {
    __shared__ int s[256];
    int i = blockIdx.x * 256 + threadIdx.x;
    int c = (i < N_NODES) ? cnt[i] : 0;
    s[threadIdx.x] = c;
    __syncthreads();
    #pragma unroll
    for (int o = 1; o < 256; o <<= 1) {
        int v = (threadIdx.x >= o) ? s[threadIdx.x - o] : 0;
        __syncthreads();
        s[threadIdx.x] += v;
        __syncthreads();
    }
    if (i < N_NODES) rowptr[i] = s[threadIdx.x] - c;   // exclusive
    if (threadIdx.x == 255) bsum[blockIdx.x] = s[255];
}

__global__ void k_scan2(int* __restrict__ bsum, int nb) {
    __shared__ int s[512];
    int t = threadIdx.x;
    int c = (t < nb) ? bsum[t] : 0;
    s[t] = c;
    __syncthreads();
    #pragma unroll
    for (int o = 1; o < 512; o <<= 1) {
        int v = (t >= o) ? s[t - o] : 0;
        __syncthreads();
        s[t] += v;
        __syncthreads();
    }
    if (t < nb) bsum[t] = s[t] - c;                    // exclusive
}

__global__ void k_scan3(int* __restrict__ rowptr, const int* __restrict__ bsum) {
    int i = blockIdx.x * 256 + threadIdx.x;
    if (i < N_NODES) rowptr[i] += bsum[blockIdx.x];
    if (i == 0) rowptr[N_NODES] = N_EDGES;
}

__global__ void k_fill(const int* __restrict__ src, const int* __restrict__ dst,
                       const int* __restrict__ rowptr, int* __restrict__ fill,
                       int* __restrict__ colidx) {
    int e = blockIdx.x * 256 + threadIdx.x;
    if (e < N_EDGES) {
        int d = dst[e];
        int pos = rowptr[d] + atomicAdd(&fill[d], 1);
        colidx[pos] = src[e];
    }
}

// ---------------- GEMM1: h1 = x @ W1  [N,128]x[128,128] ----------------
__global__ __launch_bounds__(256) void k_gemm1(const float* __restrict__ x,
                                               const float* __restrict__ W,
                                               float* __restrict__ h1) {
    __shared__ float Ws[128 * 128];
    {
        const float4* Wg = (const float4*)W;
        float4* Wl = (float4*)Ws;
        for (int i = threadIdx.x; i < 128 * 128 / 4; i += 256) Wl[i] = Wg[i];
    }
    __syncthreads();
    int wid = threadIdx.x >> 6, lane = threadIdx.x & 63;
    int r0 = (blockIdx.x * 4 + wid) * 4;   // 4 rows per wave, 16 per block
    float xlo[4], xhi[4];
    float acc0[4] = {0, 0, 0, 0}, acc1[4] = {0, 0, 0, 0};
    #pragma unroll
    for (int j = 0; j < 4; j++) {
        int r = r0 + j;
        int rc = (r < N_NODES) ? r : (N_NODES - 1);
        xlo[j] = x[rc * 128 + lane];
        xhi[j] = x[rc * 128 + 64 + lane];
    }
    #pragma unroll
    for (int k = 0; k < 64; k++) {
        float w0 = Ws[k * 128 + lane];
        float w1 = Ws[k * 128 + 64 + lane];
        #pragma unroll
        for (int j = 0; j < 4; j++) {
            float xk = lane_bcast(xlo[j], k);
            acc0[j] = fmaf(xk, w0, acc0[j]);
            acc1[j] = fmaf(xk, w1, acc1[j]);
        }
    }
    #pragma unroll
    for (int k = 0; k < 64; k++) {
        float w0 = Ws[(k + 64) * 128 + lane];
        float w1 = Ws[(k + 64) * 128 + 64 + lane];
        #pragma unroll
        for (int j = 0; j < 4; j++) {
            float xk = lane_bcast(xhi[j], k);
            acc0[j] = fmaf(xk, w0, acc0[j]);
            acc1[j] = fmaf(xk, w1, acc1[j]);
        }
    }
    #pragma unroll
    for (int j = 0; j < 4; j++) {
        int r = r0 + j;
        if (r < N_NODES) {
            h1[r * 128 + lane] = acc0[j];
            h1[r * 128 + 64 + lane] = acc1[j];
        }
    }
}

// ---------------- agg1: out1 = D^-1/2 A D^-1/2 h1 + b1 ----------------
__global__ __launch_bounds__(256) void k_agg1(const float* __restrict__ h1,
                                              const int* __restrict__ rowptr,
                                              const int* __restrict__ colidx,
                                              const float* __restrict__ dinv,
                                              const float* __restrict__ b1,
                                              float* __restrict__ out1) {
    int v = __builtin_amdgcn_readfirstlane(blockIdx.x * 4 + (threadIdx.x >> 6));
    int lane = threadIdx.x & 63;
    if (v >= N_NODES) return;
    int beg = rowptr[v], end = rowptr[v + 1];
    float a0 = 0.f, a1 = 0.f;
    for (int p = beg; p < end; p++) {
        int s = colidx[p];
        float ws = dinv[s];
        a0 = fmaf(ws, h1[s * 128 + lane], a0);
        a1 = fmaf(ws, h1[s * 128 + 64 + lane], a1);
    }
    float dv = dinv[v];
    float o0 = fmaf(dv, a0, dv * dv * h1[v * 128 + lane]) + b1[lane];
    float o1 = fmaf(dv, a1, dv * dv * h1[v * 128 + 64 + lane]) + b1[64 + lane];
    out1[v * 128 + lane] = o0;
    out1[v * 128 + 64 + lane] = o1;
}

// ---------------- BN stats ----------------
__global__ __launch_bounds__(256) void k_bnstats(const float* __restrict__ out1,
                                                 float* __restrict__ sum,
                                                 float* __restrict__ sumsq) {
    int f = threadIdx.x & 127;
    int n0 = blockIdx.x * 2 + (threadIdx.x >> 7);
    float s = 0.f, ss = 0.f;
    for (int n = n0; n < N_NODES; n += gridDim.x * 2) {
        float v = out1[n * 128 + f];
        s += v;
        ss += v * v;
    }
    __shared__ float ls[256], lss[256];
    ls[threadIdx.x] = s;
    lss[threadIdx.x] = ss;
    __syncthreads();
    if (threadIdx.x < 128) {
        atomicAdd(&sum[f], ls[threadIdx.x] + ls[threadIdx.x + 128]);
        atomicAdd(&sumsq[f], lss[threadIdx.x] + lss[threadIdx.x + 128]);
    }
}

__global__ void k_bnfinal(const float* __restrict__ sum, const float* __restrict__ sumsq,
                          const float* __restrict__ gamma, const float* __restrict__ beta,
                          float* __restrict__ scale, float* __restrict__ shift) {
    int f = threadIdx.x;   // 128 threads
    float mean = sum[f] * (1.f / N_NODES);
    float var = sumsq[f] * (1.f / N_NODES) - mean * mean;
    float rstd = rsqrtf(var + BN_EPS);
    float sc = gamma[f] * rstd;
    scale[f] = sc;
    shift[f] = beta[f] - mean * sc;
}

// ---------------- GEMM2 (BN-apply + ReLU fused on load): h2 = relu(bn(out1)) @ W2 ----------------
__global__ __launch_bounds__(256) void k_gemm2(const float* __restrict__ out1,
                                               const float* __restrict__ W2,
                                               const float* __restrict__ scale,
                                               const float* __restrict__ shift,
                                               float* __restrict__ h2) {
    int r = blockIdx.x * 256 + threadIdx.x;
    if (r >= N_NODES) return;
    float acc[F_OUT];
    #pragma unroll
    for (int c = 0; c < F_OUT; c++) acc[c] = 0.f;
    #pragma unroll
    for (int kt = 0; kt < 4; kt++) {
        float a[32];
        #pragma unroll
        for (int j = 0; j < 32; j++) {
            int k = kt * 32 + j;
            float vv = out1[r * 128 + k];
            vv = fmaf(vv, scale[k], shift[k]);
            a[j] = vv > 0.f ? vv : 0.f;
        }
        #pragma unroll
        for (int j = 0; j < 32; j++) {
            int k = kt * 32 + j;
            #pragma unroll
            for (int c = 0; c < F_OUT; c++)
                acc[c] = fmaf(a[j], W2[k * F_OUT + c], acc[c]);
        }
    }
    #pragma unroll
    for (int c = 0; c < F_OUT; c++) h2[r * F_OUT + c] = acc[c];
}

// ---------------- agg2 + b2 + log_softmax ----------------
__global__ __launch_bounds__(256) void k_agg2(const float* __restrict__ h2,
                                              const int* __restrict__ rowptr,
                                              const int* __restrict__ colidx,
                                              const float* __restrict__ dinv,
                                              const float* __restrict__ b2,
                                              float* __restrict__ out) {
    int v = __builtin_amdgcn_readfirstlane(blockIdx.x * 4 + (threadIdx.x >> 6));
    int lane = threadIdx.x & 63;
    if (v >= N_NODES) return;
    bool act = lane < F_OUT;
    int beg = rowptr[v], end = rowptr[v + 1];
    float a = 0.f;
    for (int p = beg; p < end; p++) {
        int s = colidx[p];
        float ws = dinv[s];
        float hv = act ? h2[s * F_OUT + lane] : 0.f;
        a = fmaf(ws, hv, a);
    }
    float dv = dinv[v];
    float z = act ? (fmaf(dv, a, dv * dv * h2[v * F_OUT + lane]) + b2[lane]) : -1e30f;
    float m = z;
    #pragma unroll
    for (int off = 32; off; off >>= 1) m = fmaxf(m, __shfl_xor(m, off));
    float e = act ? __expf(z - m) : 0.f;
    float ssum = e;
    #pragma unroll
    for (int off = 32; off; off >>= 1) ssum += __shfl_xor(ssum, off);
    if (act) out[v * F_OUT + lane] = z - m - __logf(ssum);
}

// ---------------- launch ----------------
extern "C" void kernel_launch(void* const* d_in, const int* in_sizes, int n_in,
                              void* d_out, int out_size, void* d_ws, size_t ws_size,
                              hipStream_t stream) {
    const float* x     = (const float*)d_in[0];
    const float* W1    = (const float*)d_in[1];
    const float* b1    = (const float*)d_in[2];
    const float* gamma = (const float*)d_in[3];
    const float* beta  = (const float*)d_in[4];
    const float* W2    = (const float*)d_in[5];
    const float* b2    = (const float*)d_in[6];
    const int* esrc    = (const int*)d_in[7];
    const int* edst    = (const int*)d_in[8];
    float* out         = (float*)d_out;

    // workspace layout
    char* w = (char*)d_ws;
    size_t off = 0;
    auto alloc = [&](size_t bytes) -> void* {
        void* p = w + off;
        off = (off + bytes + 255) & ~(size_t)255;
        return p;
    };
    int*   cnt    = (int*)alloc(N_NODES * 4);
    int*   fill   = (int*)alloc(N_NODES * 4);
    int*   rowptr = (int*)alloc((N_NODES + 1) * 4);
    int*   bsum   = (int*)alloc(512 * 4);
    float* dinv   = (float*)alloc(N_NODES * 4);
    int*   colidx = (int*)alloc((size_t)N_EDGES * 4);
    float* h1     = (float*)alloc((size_t)N_NODES * F_HID * 4);
    float* out1   = (float*)alloc((size_t)N_NODES * F_HID * 4);
    float* bnsum  = (float*)alloc(128 * 4);
    float* bnsq   = (float*)alloc(128 * 4);
    float* scale  = (float*)alloc(128 * 4);
    float* shift  = (float*)alloc(128 * 4);
    float* h2     = h1;   // h1 dead after agg1; reuse for h2 [N,40]

    (void)ws_size; (void)in_sizes; (void)n_in; (void)out_size;

    const int NB_N = (N_NODES + 255) / 256;      // 391
    const int NB_E = (N_EDGES + 255) / 256;      // 6250

    hipMemsetAsync(cnt,  0, N_NODES * 4, stream);
    hipMemsetAsync(fill, 0, N_NODES * 4, stream);
    hipMemsetAsync(bnsum, 0, 128 * 4, stream);
    hipMemsetAsync(bnsq,  0, 128 * 4, stream);

    k_count<<<NB_E, 256, 0, stream>>>(edst, cnt);
    k_dinv<<<NB_N, 256, 0, stream>>>(cnt, dinv);
    k_scan1<<<NB_N, 256, 0, stream>>>(cnt, rowptr, bsum);
    k_scan2<<<1, 512, 0, stream>>>(bsum, NB_N);
    k_scan3<<<NB_N, 256, 0, stream>>>(rowptr, bsum);
    k_fill<<<NB_E, 256, 0, stream>>>(esrc, edst, rowptr, fill, colidx);

    k_gemm1<<<(N_NODES + 15) / 16, 256, 0, stream>>>(x, W1, h1);
    k_agg1<<<(N_NODES + 3) / 4, 256, 0, stream>>>(h1, rowptr, colidx, dinv, b1, out1);

    k_bnstats<<<512, 256, 0, stream>>>(out1, bnsum, bnsq);
    k_bnfinal<<<1, 128, 0, stream>>>(bnsum, bnsq, gamma, beta, scale, shift);

    k_gemm2<<<NB_N, 256, 0, stream>>>(out1, W2, scale, shift, h2);
    k_agg2<<<(N_NODES + 3) / 4, 256, 0, stream>>>(h2, rowptr, colidx, dinv, b2, out);
}

// Round 2
// 591.390 us; speedup vs baseline: 1.4010x; 1.4010x over previous
//
#include <hip/hip_runtime.h>
#include <cstdint>
#include <cstddef>

constexpr int N_NODES = 100000;
constexpr int N_EDGES = 1600000;
constexpr int F_IN   = 128;
constexpr int F_HID  = 128;
constexpr int F_OUT  = 40;
constexpr float BN_EPS = 1e-5f;

// ---------------- CSR build ----------------
__global__ void k_count(const int* __restrict__ dst, int* __restrict__ cnt) {
    int e = blockIdx.x * 256 + threadIdx.x;
    if (e < N_EDGES) atomicAdd(&cnt[dst[e]], 1);
}

__global__ void k_dinv(const int* __restrict__ cnt, float* __restrict__ dinv) {
    int v = blockIdx.x * 256 + threadIdx.x;
    if (v < N_NODES) dinv[v] = rsqrtf((float)(cnt[v] + 1));  // +1 self-loop
}

__global__ void k_scan1(const int* __restrict__ cnt, int* __restrict__ rowptr,
                        int* __restrict__ bsum) {
    __shared__ int s[256];
    int i = blockIdx.x * 256 + threadIdx.x;
    int c = (i < N_NODES) ? cnt[i] : 0;
    s[threadIdx.x] = c;
    __syncthreads();
    #pragma unroll
    for (int o = 1; o < 256; o <<= 1) {
        int v = (threadIdx.x >= o) ? s[threadIdx.x - o] : 0;
        __syncthreads();
        s[threadIdx.x] += v;
        __syncthreads();
    }
    if (i < N_NODES) rowptr[i] = s[threadIdx.x] - c;   // exclusive
    if (threadIdx.x == 255) bsum[blockIdx.x] = s[255];
}

__global__ void k_scan2(int* __restrict__ bsum, int nb) {
    __shared__ int s[512];
    int t = threadIdx.x;
    int c = (t < nb) ? bsum[t] : 0;
    s[t] = c;
    __syncthreads();
    #pragma unroll
    for (int o = 1; o < 512; o <<= 1) {
        int v = (t >= o) ? s[t - o] : 0;
        __syncthreads();
        s[t] += v;
        __syncthreads();
    }
    if (t < nb) bsum[t] = s[t] - c;                    // exclusive
}

__global__ void k_scan3(int* __restrict__ rowptr, const int* __restrict__ bsum) {
    int i = blockIdx.x * 256 + threadIdx.x;
    if (i < N_NODES) rowptr[i] += bsum[blockIdx.x];
    if (i == 0) rowptr[N_NODES] = N_EDGES;
}

__global__ void k_fill(const int* __restrict__ src, const int* __restrict__ dst,
                       const int* __restrict__ rowptr, int* __restrict__ fill,
                       int* __restrict__ colidx) {
    int e = blockIdx.x * 256 + threadIdx.x;
    if (e < N_EDGES) {
        int d = dst[e];
        int pos = rowptr[d] + atomicAdd(&fill[d], 1);
        colidx[pos] = src[e];
    }
}

// ---------------- GEMM1: h1 = x @ W1  [N,128]x[128,128] ----------------
// Wave owns 8 rows; lane owns cols (lane, lane+64). x fetched via scalar
// loads (wave-uniform row address) -> SMEM pipe; W streamed through 16KB LDS.
__global__ __launch_bounds__(256) void k_gemm1(const float* __restrict__ x,
                                               const float* __restrict__ W,
                                               float* __restrict__ h1) {
    __shared__ float Ws[32 * 128];
    int wid = threadIdx.x >> 6, lane = threadIdx.x & 63;
    int r0 = __builtin_amdgcn_readfirstlane(blockIdx.x * 32 + wid * 8);
    float acc0[8] = {}, acc1[8] = {};
    #pragma unroll
    for (int kt = 0; kt < 4; ++kt) {
        __syncthreads();
        {
            const float4* Wg = (const float4*)(W + kt * 32 * 128);
            float4* Wl = (float4*)Ws;
            #pragma unroll
            for (int i = 0; i < 4; ++i) Wl[threadIdx.x + 256 * i] = Wg[threadIdx.x + 256 * i];
        }
        __syncthreads();
        #pragma unroll
        for (int k = 0; k < 32; ++k) {
            float w0 = Ws[k * 128 + lane];
            float w1 = Ws[k * 128 + 64 + lane];
            #pragma unroll
            for (int j = 0; j < 8; ++j) {
                float xk = x[(r0 + j) * 128 + kt * 32 + k];  // uniform -> s_load
                acc0[j] = fmaf(xk, w0, acc0[j]);
                acc1[j] = fmaf(xk, w1, acc1[j]);
            }
        }
    }
    #pragma unroll
    for (int j = 0; j < 8; ++j) {
        h1[(r0 + j) * 128 + lane] = acc0[j];
        h1[(r0 + j) * 128 + 64 + lane] = acc1[j];
    }
}

// ---------------- agg1: out1 = D^-1/2 A D^-1/2 h1 + b1 ----------------
__global__ __launch_bounds__(256) void k_agg1(const float* __restrict__ h1,
                                              const int* __restrict__ rowptr,
                                              const int* __restrict__ colidx,
                                              const float* __restrict__ dinv,
                                              const float* __restrict__ b1,
                                              float* __restrict__ out1) {
    int v = __builtin_amdgcn_readfirstlane(blockIdx.x * 4 + (threadIdx.x >> 6));
    int lane = threadIdx.x & 63;
    if (v >= N_NODES) return;
    int beg = rowptr[v], end = rowptr[v + 1];
    float a0 = 0.f, a1 = 0.f;
    for (int p = beg; p < end; p++) {
        int s = colidx[p];
        float ws = dinv[s];
        a0 = fmaf(ws, h1[s * 128 + lane], a0);
        a1 = fmaf(ws, h1[s * 128 + 64 + lane], a1);
    }
    float dv = dinv[v];
    float o0 = fmaf(dv, a0, dv * dv * h1[v * 128 + lane]) + b1[lane];
    float o1 = fmaf(dv, a1, dv * dv * h1[v * 128 + 64 + lane]) + b1[64 + lane];
    out1[v * 128 + lane] = o0;
    out1[v * 128 + 64 + lane] = o1;
}

// ---------------- BN stats ----------------
__global__ __launch_bounds__(256) void k_bnstats(const float* __restrict__ out1,
                                                 float* __restrict__ sum,
                                                 float* __restrict__ sumsq) {
    int f = threadIdx.x & 127;
    int n0 = blockIdx.x * 2 + (threadIdx.x >> 7);
    float s = 0.f, ss = 0.f;
    for (int n = n0; n < N_NODES; n += gridDim.x * 2) {
        float v = out1[n * 128 + f];
        s += v;
        ss += v * v;
    }
    __shared__ float ls[256], lss[256];
    ls[threadIdx.x] = s;
    lss[threadIdx.x] = ss;
    __syncthreads();
    if (threadIdx.x < 128) {
        atomicAdd(&sum[f], ls[threadIdx.x] + ls[threadIdx.x + 128]);
        atomicAdd(&sumsq[f], lss[threadIdx.x] + lss[threadIdx.x + 128]);
    }
}

__global__ void k_bnfinal(const float* __restrict__ sum, const float* __restrict__ sumsq,
                          const float* __restrict__ gamma, const float* __restrict__ beta,
                          float* __restrict__ scale, float* __restrict__ shift) {
    int f = threadIdx.x;   // 128 threads
    float mean = sum[f] * (1.f / N_NODES);
    float var = sumsq[f] * (1.f / N_NODES) - mean * mean;
    float rstd = rsqrtf(var + BN_EPS);
    float sc = gamma[f] * rstd;
    scale[f] = sc;
    shift[f] = beta[f] - mean * sc;
}

// ---------------- BN apply + ReLU (in-place on out1) ----------------
__global__ __launch_bounds__(256) void k_bnapply(float* __restrict__ out1,
                                                 const float* __restrict__ scale,
                                                 const float* __restrict__ shift) {
    int i = blockIdx.x * 256 + threadIdx.x;        // float4 index
    float4 v = ((float4*)out1)[i];
    float4 sc = ((const float4*)scale)[i & 31];
    float4 sh = ((const float4*)shift)[i & 31];
    v.x = fmaxf(fmaf(v.x, sc.x, sh.x), 0.f);
    v.y = fmaxf(fmaf(v.y, sc.y, sh.y), 0.f);
    v.z = fmaxf(fmaf(v.z, sc.z, sh.z), 0.f);
    v.w = fmaxf(fmaf(v.w, sc.w, sh.w), 0.f);
    ((float4*)out1)[i] = v;
}

// ---------------- GEMM2: h2 = out1b @ W2  [N,128]x[128,40] ----------------
// Wave owns 8 rows; lane (<40) owns one output col. x via scalar loads.
__global__ __launch_bounds__(256) void k_gemm2(const float* __restrict__ out1,
                                               const float* __restrict__ W2,
                                               float* __restrict__ h2) {
    __shared__ float W2s[128 * 40 + 64];
    {
        const float4* Wg = (const float4*)W2;
        float4* Wl = (float4*)W2s;
        #pragma unroll
        for (int i = 0; i < 5; ++i) Wl[threadIdx.x + 256 * i] = Wg[threadIdx.x + 256 * i];
    }
    __syncthreads();
    int wid = threadIdx.x >> 6, lane = threadIdx.x & 63;
    int r0 = __builtin_amdgcn_readfirstlane(blockIdx.x * 32 + wid * 8);
    float acc[8] = {};
    #pragma unroll 16
    for (int k = 0; k < 128; ++k) {
        float w = W2s[k * 40 + lane];   // lanes 40-63 read junk, never stored
        #pragma unroll
        for (int j = 0; j < 8; ++j) {
            float xk = out1[(r0 + j) * 128 + k];   // uniform -> s_load
            acc[j] = fmaf(xk, w, acc[j]);
        }
    }
    if (lane < F_OUT) {
        #pragma unroll
        for (int j = 0; j < 8; ++j) h2[(r0 + j) * F_OUT + lane] = acc[j];
    }
}

// ---------------- agg2 + b2 + log_softmax ----------------
__global__ __launch_bounds__(256) void k_agg2(const float* __restrict__ h2,
                                              const int* __restrict__ rowptr,
                                              const int* __restrict__ colidx,
                                              const float* __restrict__ dinv,
                                              const float* __restrict__ b2,
                                              float* __restrict__ out) {
    int v = __builtin_amdgcn_readfirstlane(blockIdx.x * 4 + (threadIdx.x >> 6));
    int lane = threadIdx.x & 63;
    if (v >= N_NODES) return;
    bool act = lane < F_OUT;
    int beg = rowptr[v], end = rowptr[v + 1];
    float a = 0.f;
    for (int p = beg; p < end; p++) {
        int s = colidx[p];
        float ws = dinv[s];
        float hv = act ? h2[s * F_OUT + lane] : 0.f;
        a = fmaf(ws, hv, a);
    }
    float dv = dinv[v];
    float z = act ? (fmaf(dv, a, dv * dv * h2[v * F_OUT + lane]) + b2[lane]) : -1e30f;
    float m = z;
    #pragma unroll
    for (int off = 32; off; off >>= 1) m = fmaxf(m, __shfl_xor(m, off));
    float e = act ? __expf(z - m) : 0.f;
    float ssum = e;
    #pragma unroll
    for (int off = 32; off; off >>= 1) ssum += __shfl_xor(ssum, off);
    if (act) out[v * F_OUT + lane] = z - m - __logf(ssum);
}

// ---------------- launch ----------------
extern "C" void kernel_launch(void* const* d_in, const int* in_sizes, int n_in,
                              void* d_out, int out_size, void* d_ws, size_t ws_size,
                              hipStream_t stream) {
    const float* x     = (const float*)d_in[0];
    const float* W1    = (const float*)d_in[1];
    const float* b1    = (const float*)d_in[2];
    const float* gamma = (const float*)d_in[3];
    const float* beta  = (const float*)d_in[4];
    const float* W2    = (const float*)d_in[5];
    const float* b2    = (const float*)d_in[6];
    const int* esrc    = (const int*)d_in[7];
    const int* edst    = (const int*)d_in[8];
    float* out         = (float*)d_out;

    // workspace layout
    char* w = (char*)d_ws;
    size_t off = 0;
    auto alloc = [&](size_t bytes) -> void* {
        void* p = w + off;
        off = (off + bytes + 255) & ~(size_t)255;
        return p;
    };
    int*   cnt    = (int*)alloc(N_NODES * 4);
    int*   fill   = (int*)alloc(N_NODES * 4);
    int*   rowptr = (int*)alloc((N_NODES + 1) * 4);
    int*   bsum   = (int*)alloc(512 * 4);
    float* dinv   = (float*)alloc(N_NODES * 4);
    int*   colidx = (int*)alloc((size_t)N_EDGES * 4);
    float* h1     = (float*)alloc((size_t)N_NODES * F_HID * 4);
    float* out1   = (float*)alloc((size_t)N_NODES * F_HID * 4);
    float* bnsum  = (float*)alloc(128 * 4);
    float* bnsq   = (float*)alloc(128 * 4);
    float* scale  = (float*)alloc(128 * 4);
    float* shift  = (float*)alloc(128 * 4);
    float* h2     = h1;   // h1 dead after agg1+bnapply; reuse for h2 [N,40]

    (void)ws_size; (void)in_sizes; (void)n_in; (void)out_size;

    const int NB_N = (N_NODES + 255) / 256;      // 391
    const int NB_E = (N_EDGES + 255) / 256;      // 6250

    hipMemsetAsync(cnt,  0, N_NODES * 4, stream);
    hipMemsetAsync(fill, 0, N_NODES * 4, stream);
    hipMemsetAsync(bnsum, 0, 128 * 4, stream);
    hipMemsetAsync(bnsq,  0, 128 * 4, stream);

    k_count<<<NB_E, 256, 0, stream>>>(edst, cnt);
    k_dinv<<<NB_N, 256, 0, stream>>>(cnt, dinv);
    k_scan1<<<NB_N, 256, 0, stream>>>(cnt, rowptr, bsum);
    k_scan2<<<1, 512, 0, stream>>>(bsum, NB_N);
    k_scan3<<<NB_N, 256, 0, stream>>>(rowptr, bsum);
    k_fill<<<NB_E, 256, 0, stream>>>(esrc, edst, rowptr, fill, colidx);

    k_gemm1<<<N_NODES / 32, 256, 0, stream>>>(x, W1, h1);               // 3125 blocks
    k_agg1<<<(N_NODES + 3) / 4, 256, 0, stream>>>(h1, rowptr, colidx, dinv, b1, out1);

    k_bnstats<<<512, 256, 0, stream>>>(out1, bnsum, bnsq);
    k_bnfinal<<<1, 128, 0, stream>>>(bnsum, bnsq, gamma, beta, scale, shift);
    k_bnapply<<<N_NODES * F_HID / 4 / 256, 256, 0, stream>>>(out1, scale, shift);

    k_gemm2<<<N_NODES / 32, 256, 0, stream>>>(out1, W2, h2);            // 3125 blocks
    k_agg2<<<(N_NODES + 3) / 4, 256, 0, stream>>>(h2, rowptr, colidx, dinv, b2, out);
}

// Round 3
// 513.059 us; speedup vs baseline: 1.6149x; 1.1527x over previous
//
#include <hip/hip_runtime.h>
#include <cstdint>
#include <cstddef>

constexpr int N_NODES = 100000;
constexpr int N_EDGES = 1600000;
constexpr int F_IN   = 128;
constexpr int F_HID  = 128;
constexpr int F_OUT  = 40;
constexpr float BN_EPS = 1e-5f;

typedef unsigned int uint;
typedef unsigned short ushort;

// ---------------- helpers ----------------
__device__ inline uint bf16_rne(float f) {
    uint u = __float_as_uint(f);
    return (u + 0x7fffu + ((u >> 16) & 1u)) >> 16;
}
__device__ inline float bf_lo(uint u) { return __uint_as_float(u << 16); }
__device__ inline float bf_hi(uint u) { return __uint_as_float(u & 0xffff0000u); }

// ---------------- CSR build ----------------
__global__ void k_count(const int* __restrict__ dst, int* __restrict__ cnt) {
    int e = blockIdx.x * 256 + threadIdx.x;
    if (e < N_EDGES) atomicAdd(&cnt[dst[e]], 1);
}

__global__ void k_dinv(const int* __restrict__ cnt, float* __restrict__ dinv) {
    int v = blockIdx.x * 256 + threadIdx.x;
    if (v < N_NODES) dinv[v] = rsqrtf((float)(cnt[v] + 1));  // +1 self-loop
}

__global__ void k_scan1(const int* __restrict__ cnt, int* __restrict__ rowptr,
                        int* __restrict__ bsum) {
    __shared__ int s[256];
    int i = blockIdx.x * 256 + threadIdx.x;
    int c = (i < N_NODES) ? cnt[i] : 0;
    s[threadIdx.x] = c;
    __syncthreads();
    #pragma unroll
    for (int o = 1; o < 256; o <<= 1) {
        int v = (threadIdx.x >= o) ? s[threadIdx.x - o] : 0;
        __syncthreads();
        s[threadIdx.x] += v;
        __syncthreads();
    }
    if (i < N_NODES) rowptr[i] = s[threadIdx.x] - c;   // exclusive
    if (threadIdx.x == 255) bsum[blockIdx.x] = s[255];
}

__global__ void k_scan2(int* __restrict__ bsum, int nb) {
    __shared__ int s[512];
    int t = threadIdx.x;
    int c = (t < nb) ? bsum[t] : 0;
    s[t] = c;
    __syncthreads();
    #pragma unroll
    for (int o = 1; o < 512; o <<= 1) {
        int v = (t >= o) ? s[t - o] : 0;
        __syncthreads();
        s[t] += v;
        __syncthreads();
    }
    if (t < nb) bsum[t] = s[t] - c;                    // exclusive
}

__global__ void k_scan3(int* __restrict__ rowptr, const int* __restrict__ bsum) {
    int i = blockIdx.x * 256 + threadIdx.x;
    if (i < N_NODES) rowptr[i] += bsum[blockIdx.x];
    if (i == 0) rowptr[N_NODES] = N_EDGES;
}

__global__ void k_fill(const int* __restrict__ src, const int* __restrict__ dst,
                       const int* __restrict__ rowptr, int* __restrict__ fill,
                       int* __restrict__ colidx) {
    int e = blockIdx.x * 256 + threadIdx.x;
    if (e < N_EDGES) {
        int d = dst[e];
        int pos = rowptr[d] + atomicAdd(&fill[d], 1);
        colidx[pos] = src[e];
    }
}

// ---------------- GEMM1: h1s = dinv*(x @ W1), bf16x2 packed ----------------
// Wave owns 8 rows; lane owns cols (2*lane, 2*lane+1). x via wave-uniform
// scalar loads (SMEM pipe); W streamed through 16KB LDS.
__global__ __launch_bounds__(256) void k_gemm1(const float* __restrict__ x,
                                               const float* __restrict__ W,
                                               const float* __restrict__ dinv,
                                               uint* __restrict__ h1b) {
    __shared__ float Ws[32 * 128];
    int wid = threadIdx.x >> 6, lane = threadIdx.x & 63;
    int r0 = __builtin_amdgcn_readfirstlane(blockIdx.x * 32 + wid * 8);
    float acc0[8] = {}, acc1[8] = {};
    #pragma unroll
    for (int kt = 0; kt < 4; ++kt) {
        __syncthreads();
        {
            const float4* Wg = (const float4*)(W + kt * 32 * 128);
            float4* Wl = (float4*)Ws;
            #pragma unroll
            for (int i = 0; i < 4; ++i) Wl[threadIdx.x + 256 * i] = Wg[threadIdx.x + 256 * i];
        }
        __syncthreads();
        #pragma unroll
        for (int k = 0; k < 32; ++k) {
            float2 wv = ((const float2*)Ws)[k * 64 + lane];
            #pragma unroll
            for (int j = 0; j < 8; ++j) {
                float xk = x[(r0 + j) * 128 + kt * 32 + k];  // uniform -> s_load
                acc0[j] = fmaf(xk, wv.x, acc0[j]);
                acc1[j] = fmaf(xk, wv.y, acc1[j]);
            }
        }
    }
    #pragma unroll
    for (int j = 0; j < 8; ++j) {
        float dv = dinv[r0 + j];                          // uniform -> s_load
        uint pk = bf16_rne(acc0[j] * dv) | (bf16_rne(acc1[j] * dv) << 16);
        h1b[(r0 + j) * 64 + lane] = pk;
    }
}

// ---------------- agg1: out1 = dv*(sum_s h1s[s] + h1s[v]) + b1 ----------------
__global__ __launch_bounds__(256) void k_agg1(const uint* __restrict__ h1b,
                                              const int* __restrict__ rowptr,
                                              const int* __restrict__ colidx,
                                              const float* __restrict__ dinv,
                                              const float* __restrict__ b1,
                                              float* __restrict__ out1) {
    int v = __builtin_amdgcn_readfirstlane(blockIdx.x * 4 + (threadIdx.x >> 6));
    int lane = threadIdx.x & 63;
    if (v >= N_NODES) return;
    int beg = rowptr[v], end = rowptr[v + 1];
    uint us = h1b[v * 64 + lane];                     // self-loop term
    float a0 = bf_lo(us), a1 = bf_hi(us);
    int p = beg;
    for (; p + 4 <= end; p += 4) {
        int s0 = colidx[p], s1 = colidx[p + 1], s2 = colidx[p + 2], s3 = colidx[p + 3];
        uint u0 = h1b[s0 * 64 + lane];
        uint u1 = h1b[s1 * 64 + lane];
        uint u2 = h1b[s2 * 64 + lane];
        uint u3 = h1b[s3 * 64 + lane];
        a0 += bf_lo(u0) + bf_lo(u1) + bf_lo(u2) + bf_lo(u3);
        a1 += bf_hi(u0) + bf_hi(u1) + bf_hi(u2) + bf_hi(u3);
    }
    for (; p < end; ++p) {
        uint u = h1b[colidx[p] * 64 + lane];
        a0 += bf_lo(u);
        a1 += bf_hi(u);
    }
    float dv = dinv[v];
    float2 o;
    o.x = fmaf(dv, a0, b1[2 * lane]);
    o.y = fmaf(dv, a1, b1[2 * lane + 1]);
    ((float2*)out1)[v * 64 + lane] = o;
}

// ---------------- BN stats ----------------
__global__ __launch_bounds__(256) void k_bnstats(const float* __restrict__ out1,
                                                 float* __restrict__ sum,
                                                 float* __restrict__ sumsq) {
    int f = threadIdx.x & 127;
    int n0 = blockIdx.x * 2 + (threadIdx.x >> 7);
    float s = 0.f, ss = 0.f;
    for (int n = n0; n < N_NODES; n += gridDim.x * 2) {
        float v = out1[n * 128 + f];
        s += v;
        ss += v * v;
    }
    __shared__ float ls[256], lss[256];
    ls[threadIdx.x] = s;
    lss[threadIdx.x] = ss;
    __syncthreads();
    if (threadIdx.x < 128) {
        atomicAdd(&sum[f], ls[threadIdx.x] + ls[threadIdx.x + 128]);
        atomicAdd(&sumsq[f], lss[threadIdx.x] + lss[threadIdx.x + 128]);
    }
}

__global__ void k_bnfinal(const float* __restrict__ sum, const float* __restrict__ sumsq,
                          const float* __restrict__ gamma, const float* __restrict__ beta,
                          float* __restrict__ scale, float* __restrict__ shift) {
    int f = threadIdx.x;   // 128 threads
    float mean = sum[f] * (1.f / N_NODES);
    float var = sumsq[f] * (1.f / N_NODES) - mean * mean;
    float rstd = rsqrtf(var + BN_EPS);
    float sc = gamma[f] * rstd;
    scale[f] = sc;
    shift[f] = beta[f] - mean * sc;
}

// ---------------- BN apply + ReLU (in-place on out1) ----------------
__global__ __launch_bounds__(256) void k_bnapply(float* __restrict__ out1,
                                                 const float* __restrict__ scale,
                                                 const float* __restrict__ shift) {
    int i = blockIdx.x * 256 + threadIdx.x;        // float4 index
    float4 v = ((float4*)out1)[i];
    float4 sc = ((const float4*)scale)[i & 31];
    float4 sh = ((const float4*)shift)[i & 31];
    v.x = fmaxf(fmaf(v.x, sc.x, sh.x), 0.f);
    v.y = fmaxf(fmaf(v.y, sc.y, sh.y), 0.f);
    v.z = fmaxf(fmaf(v.z, sc.z, sh.z), 0.f);
    v.w = fmaxf(fmaf(v.w, sc.w, sh.w), 0.f);
    ((float4*)out1)[i] = v;
}

// ---------------- GEMM2: h2s = dinv*(out1b @ W2), bf16 ----------------
// Wave owns 8 rows; lane (<40) owns one output col. x via scalar loads.
__global__ __launch_bounds__(256) void k_gemm2(const float* __restrict__ out1,
                                               const float* __restrict__ W2,
                                               const float* __restrict__ dinv,
                                               ushort* __restrict__ h2b) {
    __shared__ float W2s[128 * 40 + 64];
    {
        const float4* Wg = (const float4*)W2;
        float4* Wl = (float4*)W2s;
        #pragma unroll
        for (int i = 0; i < 5; ++i) Wl[threadIdx.x + 256 * i] = Wg[threadIdx.x + 256 * i];
    }
    __syncthreads();
    int wid = threadIdx.x >> 6, lane = threadIdx.x & 63;
    int r0 = __builtin_amdgcn_readfirstlane(blockIdx.x * 32 + wid * 8);
    float acc[8] = {};
    #pragma unroll 16
    for (int k = 0; k < 128; ++k) {
        float w = W2s[k * 40 + lane];   // lanes 40-63 read junk, never stored
        #pragma unroll
        for (int j = 0; j < 8; ++j) {
            float xk = out1[(r0 + j) * 128 + k];   // uniform -> s_load
            acc[j] = fmaf(xk, w, acc[j]);
        }
    }
    if (lane < F_OUT) {
        #pragma unroll
        for (int j = 0; j < 8; ++j) {
            float dv = dinv[r0 + j];
            h2b[(r0 + j) * F_OUT + lane] = (ushort)bf16_rne(acc[j] * dv);
        }
    }
}

// ---------------- agg2 + b2 + log_softmax ----------------
// Lane l<20 owns feature pair (2l, 2l+1); h2 row = 20 uints = 80B.
__global__ __launch_bounds__(256) void k_agg2(const uint* __restrict__ h2u,
                                              const int* __restrict__ rowptr,
                                              const int* __restrict__ colidx,
                                              const float* __restrict__ dinv,
                                              const float* __restrict__ b2,
                                              float* __restrict__ out) {
    int v = __builtin_amdgcn_readfirstlane(blockIdx.x * 4 + (threadIdx.x >> 6));
    int lane = threadIdx.x & 63;
    if (v >= N_NODES) return;
    bool act = lane < 20;
    int li = act ? lane : 0;
    int beg = rowptr[v], end = rowptr[v + 1];
    uint us = act ? h2u[v * 20 + li] : 0u;
    float a0 = bf_lo(us), a1 = bf_hi(us);
    int p = beg;
    for (; p + 4 <= end; p += 4) {
        int s0 = colidx[p], s1 = colidx[p + 1], s2 = colidx[p + 2], s3 = colidx[p + 3];
        uint u0 = act ? h2u[s0 * 20 + li] : 0u;
        uint u1 = act ? h2u[s1 * 20 + li] : 0u;
        uint u2 = act ? h2u[s2 * 20 + li] : 0u;
        uint u3 = act ? h2u[s3 * 20 + li] : 0u;
        a0 += bf_lo(u0) + bf_lo(u1) + bf_lo(u2) + bf_lo(u3);
        a1 += bf_hi(u0) + bf_hi(u1) + bf_hi(u2) + bf_hi(u3);
    }
    for (; p < end; ++p) {
        uint u = act ? h2u[colidx[p] * 20 + li] : 0u;
        a0 += bf_lo(u);
        a1 += bf_hi(u);
    }
    float dv = dinv[v];
    float z0 = act ? fmaf(dv, a0, b2[2 * li])     : -1e30f;
    float z1 = act ? fmaf(dv, a1, b2[2 * li + 1]) : -1e30f;
    float m = fmaxf(z0, z1);
    #pragma unroll
    for (int off = 32; off; off >>= 1) m = fmaxf(m, __shfl_xor(m, off));
    float e = act ? (__expf(z0 - m) + __expf(z1 - m)) : 0.f;
    float ssum = e;
    #pragma unroll
    for (int off = 32; off; off >>= 1) ssum += __shfl_xor(ssum, off);
    float ls = __logf(ssum);
    if (act) {
        float2 o;
        o.x = z0 - m - ls;
        o.y = z1 - m - ls;
        ((float2*)out)[v * 20 + li] = o;
    }
}

// ---------------- launch ----------------
extern "C" void kernel_launch(void* const* d_in, const int* in_sizes, int n_in,
                              void* d_out, int out_size, void* d_ws, size_t ws_size,
                              hipStream_t stream) {
    const float* x     = (const float*)d_in[0];
    const float* W1    = (const float*)d_in[1];
    const float* b1    = (const float*)d_in[2];
    const float* gamma = (const float*)d_in[3];
    const float* beta  = (const float*)d_in[4];
    const float* W2    = (const float*)d_in[5];
    const float* b2    = (const float*)d_in[6];
    const int* esrc    = (const int*)d_in[7];
    const int* edst    = (const int*)d_in[8];
    float* out         = (float*)d_out;

    // workspace layout
    char* w = (char*)d_ws;
    size_t off = 0;
    auto alloc = [&](size_t bytes) -> void* {
        void* p = w + off;
        off = (off + bytes + 255) & ~(size_t)255;
        return p;
    };
    int*   cnt    = (int*)alloc(N_NODES * 4);
    int*   fill   = (int*)alloc(N_NODES * 4);
    int*   rowptr = (int*)alloc((N_NODES + 1) * 4);
    int*   bsum   = (int*)alloc(512 * 4);
    float* dinv   = (float*)alloc(N_NODES * 4);
    int*   colidx = (int*)alloc((size_t)N_EDGES * 4);
    uint*  h1b    = (uint*)alloc((size_t)N_NODES * 64 * 4);    // bf16x2 [N,128]
    float* out1   = (float*)alloc((size_t)N_NODES * F_HID * 4);
    float* bnsum  = (float*)alloc(128 * 4);
    float* bnsq   = (float*)alloc(128 * 4);
    float* scale  = (float*)alloc(128 * 4);
    float* shift  = (float*)alloc(128 * 4);
    ushort* h2b   = (ushort*)h1b;   // h1b dead after agg1; reuse: bf16 [N,40]

    (void)ws_size; (void)in_sizes; (void)n_in; (void)out_size;

    const int NB_N = (N_NODES + 255) / 256;      // 391
    const int NB_E = (N_EDGES + 255) / 256;      // 6250

    hipMemsetAsync(cnt,  0, N_NODES * 4, stream);
    hipMemsetAsync(fill, 0, N_NODES * 4, stream);
    hipMemsetAsync(bnsum, 0, 128 * 4, stream);
    hipMemsetAsync(bnsq,  0, 128 * 4, stream);

    k_count<<<NB_E, 256, 0, stream>>>(edst, cnt);
    k_dinv<<<NB_N, 256, 0, stream>>>(cnt, dinv);
    k_scan1<<<NB_N, 256, 0, stream>>>(cnt, rowptr, bsum);
    k_scan2<<<1, 512, 0, stream>>>(bsum, NB_N);
    k_scan3<<<NB_N, 256, 0, stream>>>(rowptr, bsum);
    k_fill<<<NB_E, 256, 0, stream>>>(esrc, edst, rowptr, fill, colidx);

    k_gemm1<<<N_NODES / 32, 256, 0, stream>>>(x, W1, dinv, h1b);        // 3125 blocks
    k_agg1<<<(N_NODES + 3) / 4, 256, 0, stream>>>(h1b, rowptr, colidx, dinv, b1, out1);

    k_bnstats<<<512, 256, 0, stream>>>(out1, bnsum, bnsq);
    k_bnfinal<<<1, 128, 0, stream>>>(bnsum, bnsq, gamma, beta, scale, shift);
    k_bnapply<<<N_NODES * F_HID / 4 / 256, 256, 0, stream>>>(out1, scale, shift);

    k_gemm2<<<N_NODES / 32, 256, 0, stream>>>(out1, W2, dinv, (ushort*)h2b);
    k_agg2<<<(N_NODES + 3) / 4, 256, 0, stream>>>((const uint*)h2b, rowptr, colidx, dinv, b2, out);
}